// Round 3
// baseline (447.358 us; speedup 1.0000x reference)
//
#include <hip/hip_runtime.h>
#include <stdint.h>

// ---------------------------------------------------------------------------
// DataEmbedding_ALLPE_Weighted on MI355X (gfx950)  — round 6
//
// Round-5 post-mortem: all rounds ran 2 waves/SIMD (acc 128 AGPR + ~104 VGPR
// = 232 combined on the unified file); BK=32 swizzle caused 4-way LDS
// conflicts (6.3M); and B staged via LDS has ZERO intra-block reuse (each
// element hits exactly one lane's register) — pure round-trip overhead.
// Fix: B loaded straight from L2 into registers (short8, 16 lines/wave-load);
// A stays in a tiny 8 KB LDS double-buffer (4x cross-wave reuse), BK=64,
// ONE barrier per K-step whose vmcnt(0) drains only 2 A-DMA loads issued a
// full 64-MFMA phase earlier. 8-slot XOR swizzle (conflict-free). setprio
// around MFMA cluster. prep/bias2/pe_tables merged into one launch.
// ---------------------------------------------------------------------------

typedef unsigned short u16;
using short8  = __attribute__((ext_vector_type(8))) short;
using floatx4 = __attribute__((ext_vector_type(4))) float;
typedef __attribute__((address_space(1))) const unsigned int u32_as1;
typedef __attribute__((address_space(3))) unsigned int       u32_as3;

static __device__ __forceinline__ u16 f2b(float f) {
  unsigned u = __float_as_uint(f);
  u += 0x7FFFu + ((u >> 16) & 1u);          // RNE
  return (u16)(u >> 16);
}
static __device__ __forceinline__ float b2f(u16 h) {
  return __uint_as_float(((unsigned)h) << 16);
}

// ------------------------------------------------- merged prep (one launch)
// blocks [0,12800): prep mats; [12800,12802): bias2; [12802,13826): pe tables
__global__ __launch_bounds__(256) void prep_all(
    const float* __restrict__ conv_w, const float* __restrict__ mixer_w,
    const float* __restrict__ tproj_w, const float* __restrict__ tape_pos,
    const float* __restrict__ tproj_b, const float* __restrict__ mixer_b,
    const float* __restrict__ learned_pe,
    const float* __restrict__ gf, const float* __restrict__ bf_,
    const float* __restrict__ gl, const float* __restrict__ bl,
    u16* __restrict__ W1, u16* __restrict__ A_m1, u16* __restrict__ M2t,
    u16* __restrict__ tprojT, u16* __restrict__ tape_bf,
    float* __restrict__ bias2, u16* __restrict__ pf_tab,
    u16* __restrict__ pl_tab) {
  const int bx = blockIdx.x;
  if (bx < 12800) {
    int i = bx * 256 + threadIdx.x;
    if (i < 393216) {                                    // W1: 512*768
      int d = i / 768, rem = i - d * 768;
      int j = rem >> 8, c = rem & 255;
      W1[i] = f2b(conv_w[(d * 256 + c) * 3 + j]);
    } else if (i < 393216 + 262144) {
      int k = i - 393216; int p = k >> 9, r = k & 511;
      A_m1[k] = f2b(mixer_w[p * 1024 + r]);
    } else if (i < 393216 + 524288) {
      int k = i - 393216 - 262144; int p = k >> 9, r = k & 511;
      M2t[k] = f2b(mixer_w[p * 1024 + 512 + r]);
    } else if (i < 393216 + 786432) {
      int k = i - 393216 - 524288; int q = k >> 9, r = k & 511;
      tprojT[k] = f2b(tproj_w[r * 512 + q]);
    } else if (i < 393216 + 786432 + 2097152) {
      int k = i - 393216 - 786432;
      tape_bf[k] = f2b(tape_pos[k]);
    }
    return;
  }
  if (bx < 12802) {
    int p = (bx - 12800) * 256 + threadIdx.x;
    if (p < 512) {
      float s = mixer_b[p];
      for (int r = 0; r < 512; ++r) s += mixer_w[p * 1024 + r] * tproj_b[r];
      bias2[p] = s;
    }
    return;
  }
  // pe tables
  int row = (bx - 12802) * 4 + (threadIdx.x >> 6);
  int lane = threadIdx.x & 63;
  size_t base = (size_t)row * 512 + lane * 8;
  float v[8]; float s1 = 0.f, s2 = 0.f;
  #pragma unroll
  for (int e = 0; e < 8; ++e) {
    int d = lane * 8 + e;
    int de = d & ~1;
    float div = expf((float)de * (-9.210340371976184f / 512.f));
    float ang = (float)row * div;
    v[e] = (d & 1) ? cosf(ang) : sinf(ang);
    s1 += v[e]; s2 += v[e] * v[e];
  }
  #pragma unroll
  for (int off = 32; off; off >>= 1) { s1 += __shfl_xor(s1, off); s2 += __shfl_xor(s2, off); }
  float mean = s1 * (1.f / 512.f);
  float inv = rsqrtf(fmaxf(s2 * (1.f / 512.f) - mean * mean, 0.f) + 1e-5f);
  short8 o;
  #pragma unroll
  for (int e = 0; e < 8; ++e) {
    int d = lane * 8 + e;
    o[e] = (short)f2b(gf[d] * ((v[e] - mean) * inv) + bf_[d]);
  }
  *(short8*)(pf_tab + base) = o;
  const float4* lp = (const float4*)(learned_pe + base);
  float4 a = lp[0], bq = lp[1];
  float u[8] = {a.x, a.y, a.z, a.w, bq.x, bq.y, bq.z, bq.w};
  s1 = 0.f; s2 = 0.f;
  #pragma unroll
  for (int e = 0; e < 8; ++e) { s1 += u[e]; s2 += u[e] * u[e]; }
  #pragma unroll
  for (int off = 32; off; off >>= 1) { s1 += __shfl_xor(s1, off); s2 += __shfl_xor(s2, off); }
  mean = s1 * (1.f / 512.f);
  inv = rsqrtf(fmaxf(s2 * (1.f / 512.f) - mean * mean, 0.f) + 1e-5f);
  #pragma unroll
  for (int e = 0; e < 8; ++e) {
    int d = lane * 8 + e;
    o[e] = (short)f2b(gl[d] * ((u[e] - mean) * inv) + bl[d]);
  }
  *(short8*)(pl_tab + base) = o;
}

// -------------------------------------------------------------- features
__global__ __launch_bounds__(256) void feat_kernel(
    const float* __restrict__ x, u16* __restrict__ comb) {
  __shared__ float sx[87 * 32];
  const int b = blockIdx.y, l0 = blockIdx.x * 64;
  for (int idx = threadIdx.x; idx < 87 * 32; idx += 256) {
    int r = idx >> 5, c = idx & 31;
    int ls = l0 - 23 + r; if (ls < 0) ls = 0;
    sx[idx] = x[((size_t)b * 4096 + ls) * 32 + c];
  }
  __syncthreads();
  const int c = threadIdx.x & 31, lr0 = threadIdx.x >> 5;
  for (int pass = 0; pass < 8; ++pass) {
    int lr = pass * 8 + lr0;
    int l = l0 + lr;
    float w[24];
    float s = 0.f, mx = -3.4e38f, mn = 3.4e38f;
    #pragma unroll
    for (int i = 0; i < 24; ++i) {
      float v = sx[(lr + i) * 32 + c];
      w[i] = v; s += v; mx = fmaxf(mx, v); mn = fminf(mn, v);
    }
    float mean = s * (1.f / 24.f);
    float ssd = 0.f;
    #pragma unroll
    for (int i = 0; i < 24; ++i) { float d = w[i] - mean; ssd += d * d; }
    float sd = sqrtf(fmaxf(ssd, 0.f) * (1.f / 23.f));
    float xv = w[23];
    float lag3 = xv - sx[(lr + 20) * 32 + c];
    float lag5 = xv - sx[(lr + 18) * 32 + c];
    float lag7 = xv - sx[(lr + 16) * 32 + c];
    size_t base = ((size_t)b * 4096 + l) * 256 + c;
    comb[base +   0] = f2b(xv);
    comb[base +  32] = f2b(mean);
    comb[base +  64] = f2b(mx);
    comb[base +  96] = f2b(mn);
    comb[base + 128] = f2b(sd);
    comb[base + 160] = f2b(lag3);
    comb[base + 192] = f2b(lag5);
    comb[base + 224] = f2b(lag7);
  }
}

// ------------------------------------------------------- small bf16 GEMM
__global__ __launch_bounds__(256) void gemm_bt(
    const u16* __restrict__ A, const u16* __restrict__ Bt,
    void* __restrict__ outp, int K, int ldc,
    const float* __restrict__ bias, int outBf16) {
  __shared__ __align__(16) u16 lA[128 * 64];
  __shared__ __align__(16) u16 lB[128 * 64];
  const int tid = threadIdx.x;
  const int m0 = blockIdx.x * 128, n0 = blockIdx.y * 128;
  const int wave = tid >> 6, lane = tid & 63;
  const int wm = (wave & 1) * 64, wn = (wave >> 1) * 64;
  const int quad = lane >> 4, r16 = lane & 15;
  const int rowT = tid >> 3, col8 = tid & 7;

  floatx4 acc[4][4];
  #pragma unroll
  for (int i = 0; i < 4; ++i)
    #pragma unroll
    for (int j = 0; j < 4; ++j) acc[i][j] = (floatx4){0.f, 0.f, 0.f, 0.f};

  for (int kk = 0; kk < K; kk += 64) {
    __syncthreads();
    #pragma unroll
    for (int it = 0; it < 4; ++it) {
      int rr = it * 32 + rowT;
      const u16* ga = A  + (size_t)(m0 + rr) * K + kk + col8 * 8;
      const u16* gb = Bt + (size_t)(n0 + rr) * K + kk + col8 * 8;
      __builtin_amdgcn_global_load_lds((u32_as1*)ga, (u32_as3*)&lA[rr * 64 + col8 * 8], 16, 0, 0);
      __builtin_amdgcn_global_load_lds((u32_as1*)gb, (u32_as3*)&lB[rr * 64 + col8 * 8], 16, 0, 0);
    }
    __syncthreads();
    #pragma unroll
    for (int ks = 0; ks < 64; ks += 32) {
      short8 af[4], bfr[4];
      #pragma unroll
      for (int i = 0; i < 4; ++i)
        af[i] = *(const short8*)&lA[(wm + i * 16 + r16) * 64 + ks + quad * 8];
      #pragma unroll
      for (int j = 0; j < 4; ++j)
        bfr[j] = *(const short8*)&lB[(wn + j * 16 + r16) * 64 + ks + quad * 8];
      #pragma unroll
      for (int i = 0; i < 4; ++i)
        #pragma unroll
        for (int j = 0; j < 4; ++j)
          acc[i][j] = __builtin_amdgcn_mfma_f32_16x16x32_bf16(af[i], bfr[j], acc[i][j], 0, 0, 0);
    }
  }
  #pragma unroll
  for (int i = 0; i < 4; ++i) {
    #pragma unroll
    for (int rr = 0; rr < 4; ++rr) {
      int m = m0 + wm + i * 16 + quad * 4 + rr;
      #pragma unroll
      for (int j = 0; j < 4; ++j) {
        int n = n0 + wn + j * 16 + r16;
        float v = acc[i][j][rr];
        if (bias) v += bias[n];
        if (outBf16) ((u16*)outp)[(size_t)m * ldc + n] = f2b(v);
        else         ((float*)outp)[(size_t)m * ldc + n] = v;
      }
    }
  }
}

// ---------------------------------------------------------------------------
// Fused wide-N GEMM kernels. Block = 64 m-rows x 512 n-cols, 256 threads
// (4 waves, wave w owns n-strip [w*128, w*128+128)).  Operand-swapped MFMA:
//   D = mfma(B_frag, A_frag):  lane(q,r): m = i*16 + r,  n = jj*16 + q*4 + rr
//
// B (weights, L2-resident) is loaded DIRECTLY into registers (short8): each
// element is consumed by one lane only (no intra-block reuse) -> LDS staging
// for B was pure overhead.  A (4x cross-wave reuse) stays in LDS: 8 KB tile,
// BK=64, double-buffered, 2 global_load_lds/thread, ONE barrier per K-step.
// XOR swizzle (8 chunks/row): slot(row,c) holds global chunk c^(row&7);
// read chunk (s*4+quad)^(row&7)  -> conflict-free (2-way max).
// LDS: A0 @0 (8K) + A1 @8192 (8K), union with lT[64][520] (66.5K, epilogue).
// ---------------------------------------------------------------------------

#define STAGE_A(BUFOFF, SRCEXPR)                                               \
  _Pragma("unroll")                                                            \
  for (int it = 0; it < 2; ++it) {                                             \
    int id = it * 256 + tid, row = id >> 3, c = id & 7;                        \
    int cg = ((c ^ (row & 7)) << 3); (void)cg;                                 \
    const u16* gsrc = (SRCEXPR);                                               \
    __builtin_amdgcn_global_load_lds((u32_as1*)gsrc,                           \
        (u32_as3*)(smem + (BUFOFF) + id * 16), 16, 0, 0);                      \
  }

// ------------------------- conv GEMM + bias + LN -> ce (bf16) -------------
__global__ __launch_bounds__(256, 2) void gemm_conv_ln(
    const u16* __restrict__ comb, const u16* __restrict__ W1,
    const float* __restrict__ conv_b, const float* __restrict__ g_c,
    const float* __restrict__ b_c, u16* __restrict__ ce) {
  __shared__ __align__(16) char smem[66560];
  __shared__ float sG[512], sB[512], sBias[512];
  u16* lT = (u16*)smem;                       // [64][520]

  const int tid = threadIdx.x;
  if (tid < 128) {
    ((float4*)sG)[tid]    = ((const float4*)g_c)[tid];
    ((float4*)sB)[tid]    = ((const float4*)b_c)[tid];
    ((float4*)sBias)[tid] = ((const float4*)conv_b)[tid];
  }
  const int m0 = blockIdx.x * 64;
  const int b = m0 >> 12, l0 = m0 & 4095;
  const int w = tid >> 6, lane = tid & 63;
  const int quad = lane >> 4, r16 = lane & 15;
  const int wn = w * 128;
  // per-lane B base: row n = wn + jj*16 + r16, chunk quad
  const u16* bw = W1 + (size_t)(wn + r16) * 768 + quad * 8;

  floatx4 acc[4][8];
  #pragma unroll
  for (int i = 0; i < 4; ++i)
    #pragma unroll
    for (int jj = 0; jj < 8; ++jj) acc[i][jj] = (floatx4){0.f, 0.f, 0.f, 0.f};

  // prologue: stage K-tile 0 into buffer 0 (kk=0 -> jsh=0, kc=0)
  STAGE_A(0, comb + (((size_t)b * 4096 + ((l0 + row - 1 + 4096) & 4095)) << 8) + cg)
  __syncthreads();

  for (int t = 0; t < 12; ++t) {
    const int kk = t * 64;
    const u16* lAc = (const u16*)(smem + (t & 1) * 8192);
    if (t + 1 < 12) {
      const int kk2 = kk + 64;
      const int jsh = kk2 >> 8, kc = kk2 & 255;
      STAGE_A((1 - (t & 1)) * 8192,
          comb + (((size_t)b * 4096 + ((l0 + row + jsh - 1 + 4096) & 4095)) << 8) + kc + cg)
    }
    #pragma unroll
    for (int s = 0; s < 2; ++s) {
      short8 bf[8], af[4];
      #pragma unroll
      for (int jj = 0; jj < 8; ++jj)
        bf[jj] = *(const short8*)(bw + (size_t)jj * 12288 + kk + s * 32);
      #pragma unroll
      for (int i = 0; i < 4; ++i) {
        int row = i * 16 + r16;
        af[i] = *(const short8*)((const u16*)lAc + row * 64 + (((s * 4 + quad) ^ (row & 7)) << 3));
      }
      __builtin_amdgcn_s_setprio(1);
      #pragma unroll
      for (int jj = 0; jj < 8; ++jj)
        #pragma unroll
        for (int i = 0; i < 4; ++i)
          acc[i][jj] = __builtin_amdgcn_mfma_f32_16x16x32_bf16(bf[jj], af[i], acc[i][jj], 0, 0, 0);
      __builtin_amdgcn_s_setprio(0);
    }
    __syncthreads();   // fences buf^1 (stage done) and frees buf cur for t+1
  }

  // transpose to lT with conv bias added (pre-LN)
  #pragma unroll
  for (int jj = 0; jj < 8; ++jj) {
    int n = wn + jj * 16 + quad * 4;
    float4 b4 = *(const float4*)&sBias[n];
    #pragma unroll
    for (int i = 0; i < 4; ++i) {
      ushort4 pk;
      pk.x = f2b(acc[i][jj][0] + b4.x);
      pk.y = f2b(acc[i][jj][1] + b4.y);
      pk.z = f2b(acc[i][jj][2] + b4.z);
      pk.w = f2b(acc[i][jj][3] + b4.w);
      *(ushort4*)(lT + (size_t)(i * 16 + r16) * 520 + n) = pk;
    }
  }
  __syncthreads();
  // two-pass LN (no per-thread array -> no scratch)
  const int orow = tid >> 2, part = tid & 3;
  const u16* rowp = lT + (size_t)orow * 520;
  float s1 = 0.f, s2 = 0.f;
  #pragma unroll
  for (int k = 0; k < 16; ++k) {
    short8 t8 = *(const short8*)(rowp + (part + k * 4) * 8);
    #pragma unroll
    for (int e = 0; e < 8; ++e) {
      float f = b2f((u16)t8[e]); s1 += f; s2 += f * f;
    }
  }
  s1 += __shfl_xor(s1, 1); s2 += __shfl_xor(s2, 1);
  s1 += __shfl_xor(s1, 2); s2 += __shfl_xor(s2, 2);
  float mean = s1 * (1.f / 512.f);
  float inv = rsqrtf(fmaxf(s2 * (1.f / 512.f) - mean * mean, 0.f) + 1e-5f);
  size_t mrow = (size_t)(m0 + orow) * 512;
  #pragma unroll
  for (int k = 0; k < 16; ++k) {
    int c8 = part + k * 4;
    short8 t8 = *(const short8*)(rowp + c8 * 8);
    short8 o;
    #pragma unroll
    for (int e = 0; e < 8; ++e) {
      int d = c8 * 8 + e;
      o[e] = (short)f2b(sG[d] * ((b2f((u16)t8[e]) - mean) * inv) + sB[d]);
    }
    *(short8*)(ce + mrow + c8 * 8) = o;
  }
}

// --------- pre GEMM + ctab + LN(g_t,b_t) + weighted sum -> out (fp32) -----
__global__ __launch_bounds__(256, 2) void gemm_pre_final(
    const u16* __restrict__ ceA, const u16* __restrict__ Wf,
    const u16* __restrict__ ctab_bf, const u16* __restrict__ pf_tab,
    const u16* __restrict__ pl_tab, const float* __restrict__ g_t,
    const float* __restrict__ b_t, const float* __restrict__ wp,
    float* __restrict__ out) {
  __shared__ __align__(16) char smem[66560];
  __shared__ float sG[512], sB[512];
  u16* lT = (u16*)smem;

  const int tid = threadIdx.x;
  if (tid < 128) {
    ((float4*)sG)[tid] = ((const float4*)g_t)[tid];
    ((float4*)sB)[tid] = ((const float4*)b_t)[tid];
  }
  const int m0 = blockIdx.x * 64;
  const int l0m = m0 & 4095;
  const int w = tid >> 6, lane = tid & 63;
  const int quad = lane >> 4, r16 = lane & 15;
  const int wn = w * 128;
  const u16* bw = Wf + (size_t)(wn + r16) * 512 + quad * 8;

  floatx4 acc[4][8];
  #pragma unroll
  for (int i = 0; i < 4; ++i)
    #pragma unroll
    for (int jj = 0; jj < 8; ++jj) acc[i][jj] = (floatx4){0.f, 0.f, 0.f, 0.f};

  // prologue
  STAGE_A(0, ceA + (size_t)(m0 + row) * 512 + cg)
  __syncthreads();

  for (int t = 0; t < 8; ++t) {
    const int kk = t * 64;
    const u16* lAc = (const u16*)(smem + (t & 1) * 8192);
    if (t + 1 < 8) {
      STAGE_A((1 - (t & 1)) * 8192,
          ceA + (size_t)(m0 + row) * 512 + kk + 64 + cg)
    }
    #pragma unroll
    for (int s = 0; s < 2; ++s) {
      short8 bf[8], af[4];
      #pragma unroll
      for (int jj = 0; jj < 8; ++jj)
        bf[jj] = *(const short8*)(bw + (size_t)jj * 8192 + kk + s * 32);
      #pragma unroll
      for (int i = 0; i < 4; ++i) {
        int row = i * 16 + r16;
        af[i] = *(const short8*)((const u16*)lAc + row * 64 + (((s * 4 + quad) ^ (row & 7)) << 3));
      }
      __builtin_amdgcn_s_setprio(1);
      #pragma unroll
      for (int jj = 0; jj < 8; ++jj)
        #pragma unroll
        for (int i = 0; i < 4; ++i)
          acc[i][jj] = __builtin_amdgcn_mfma_f32_16x16x32_bf16(bf[jj], af[i], acc[i][jj], 0, 0, 0);
      __builtin_amdgcn_s_setprio(0);
    }
    __syncthreads();
  }

  #pragma unroll
  for (int jj = 0; jj < 8; ++jj) {
    int n = wn + jj * 16 + quad * 4;
    #pragma unroll
    for (int i = 0; i < 4; ++i) {
      ushort4 pk;
      pk.x = f2b(acc[i][jj][0]);
      pk.y = f2b(acc[i][jj][1]);
      pk.z = f2b(acc[i][jj][2]);
      pk.w = f2b(acc[i][jj][3]);
      *(ushort4*)(lT + (size_t)(i * 16 + r16) * 520 + n) = pk;
    }
  }
  __syncthreads();
  const int orow = tid >> 2, part = tid & 3;
  const int m = m0 + orow, l = l0m + orow;
  const u16* rowp = lT + (size_t)orow * 520;
  const size_t lrow = (size_t)l * 512, mrow = (size_t)m * 512;
  // pass 1: sum/sumsq of (pre + ctab)
  float s1 = 0.f, s2 = 0.f;
  #pragma unroll
  for (int k = 0; k < 16; ++k) {
    int c8 = part + k * 4;
    short8 t8 = *(const short8*)(rowp + c8 * 8);
    short8 ct = *(const short8*)(ctab_bf + lrow + c8 * 8);
    #pragma unroll
    for (int e = 0; e < 8; ++e) {
      float f = b2f((u16)t8[e]) + b2f((u16)ct[e]);
      s1 += f; s2 += f * f;
    }
  }
  s1 += __shfl_xor(s1, 1); s2 += __shfl_xor(s2, 1);
  s1 += __shfl_xor(s1, 2); s2 += __shfl_xor(s2, 2);
  float mean = s1 * (1.f / 512.f);
  float inv = rsqrtf(fmaxf(s2 * (1.f / 512.f) - mean * mean, 0.f) + 1e-5f);

  float a0 = wp[0], a1 = wp[1], a2 = wp[2], a3 = wp[3];
  float mxw = fmaxf(fmaxf(a0, a1), fmaxf(a2, a3));
  float e0 = expf(a0 - mxw), e1 = expf(a1 - mxw), e2 = expf(a2 - mxw), e3 = expf(a3 - mxw);
  float invs = 1.f / (e0 + e1 + e2 + e3);
  float w0 = e0 * invs, w1 = e1 * invs, w2 = e2 * invs, w3 = e3 * invs;

  // pass 2: re-read LDS + ctab, add weighted ce/pf/pl, store fp32
  #pragma unroll
  for (int k = 0; k < 16; ++k) {
    int c8 = part + k * 4;
    short8 t8  = *(const short8*)(rowp + c8 * 8);
    short8 ct  = *(const short8*)(ctab_bf + lrow + c8 * 8);
    short8 c8v = *(const short8*)(ceA + mrow + c8 * 8);
    short8 pf  = *(const short8*)(pf_tab + lrow + c8 * 8);
    short8 pl  = *(const short8*)(pl_tab + lrow + c8 * 8);
    float o[8];
    #pragma unroll
    for (int e = 0; e < 8; ++e) {
      int d = c8 * 8 + e;
      float f = b2f((u16)t8[e]) + b2f((u16)ct[e]);
      float pt = sG[d] * ((f - mean) * inv) + sB[d];
      o[e] = w0 * b2f((u16)c8v[e]) + w1 * b2f((u16)pf[e]) + w2 * b2f((u16)pl[e]) + w3 * pt;
    }
    float4* op = (float4*)(out + mrow + c8 * 8);
    op[0] = make_float4(o[0], o[1], o[2], o[3]);
    op[1] = make_float4(o[4], o[5], o[6], o[7]);
  }
}

// ---------------------------------------------------------------------------
extern "C" void kernel_launch(void* const* d_in, const int* in_sizes, int n_in,
                              void* d_out, int out_size, void* d_ws, size_t ws_size,
                              hipStream_t stream) {
  const float* x          = (const float*)d_in[0];
  const float* conv_w     = (const float*)d_in[1];
  const float* conv_b     = (const float*)d_in[2];
  const float* learned_pe = (const float*)d_in[3];
  const float* tape_pos   = (const float*)d_in[4];
  const float* tproj_w    = (const float*)d_in[5];
  const float* tproj_b    = (const float*)d_in[6];
  const float* mixer_w    = (const float*)d_in[7];
  const float* mixer_b    = (const float*)d_in[8];
  const float* g_c        = (const float*)d_in[9];
  const float* b_c        = (const float*)d_in[10];
  const float* g_f        = (const float*)d_in[11];
  const float* b_f        = (const float*)d_in[12];
  const float* g_l        = (const float*)d_in[13];
  const float* b_l        = (const float*)d_in[14];
  const float* g_t        = (const float*)d_in[15];
  const float* b_t        = (const float*)d_in[16];
  const float* wp         = (const float*)d_in[17];

  char* ws = (char*)d_ws;
  u16*  comb    = (u16*)(ws + 0);             // 32 MiB
  u16*  ce      = (u16*)(ws + 33554432);      // 64 MiB
  char* S       = ws + 100663296;
  u16*  W1      = (u16*)(S + 0);              // 768 KiB
  u16*  A_m1    = (u16*)(S + 786432);         // 512 KiB
  u16*  M2t     = (u16*)(S + 1310720);        // 512 KiB
  u16*  tprojT  = (u16*)(S + 1835008);        // 512 KiB
  u16*  tape_bf = (u16*)(S + 2359296);        // 4 MiB
  u16*  Wf      = (u16*)(S + 6553600);        // 512 KiB
  u16*  ctab_bf = (u16*)(S + 7077888);        // 4 MiB
  float* bias2  = (float*)(S + 11272192);     // 2 KiB
  u16*  pf_tab  = (u16*)(S + 11274240);       // 4 MiB
  u16*  pl_tab  = (u16*)(S + 15468544);       // 4 MiB

  prep_all<<<13826, 256, 0, stream>>>(conv_w, mixer_w, tproj_w, tape_pos,
                                      tproj_b, mixer_b, learned_pe,
                                      g_f, b_f, g_l, b_l,
                                      W1, A_m1, M2t, tprojT, tape_bf,
                                      bias2, pf_tab, pl_tab);
  feat_kernel<<<dim3(64, 16), 256, 0, stream>>>(x, comb);
  // Wf = M1 @ tproj_w   (bf16)
  gemm_bt<<<dim3(4, 4), 256, 0, stream>>>(A_m1, tprojT, Wf, 512, 512, nullptr, 1);
  // ctab = tape_pos @ M2^T + bias2   (bf16)
  gemm_bt<<<dim3(32, 4), 256, 0, stream>>>(tape_bf, M2t, ctab_bf, 512, 512, bias2, 1);
  // fused conv + LN -> ce   (register-B, dbuf-A, 1 barrier / K-step)
  gemm_conv_ln<<<1024, 256, 0, stream>>>(comb, W1, conv_b, g_c, b_c, ce);
  // fused pre + LN + weighted sum -> out
  gemm_pre_final<<<1024, 256, 0, stream>>>(ce, Wf, ctab_bf, pf_tab, pl_tab,
                                           g_t, b_t, wp, (float*)d_out);
}

// Round 4
// 387.919 us; speedup vs baseline: 1.1532x; 1.1532x over previous
//
#include <hip/hip_runtime.h>
#include <stdint.h>

// ---------------------------------------------------------------------------
// DataEmbedding_ALLPE_Weighted on MI355X (gfx950)  — round 7
//
// Rounds 4-6 lesson: the round-3 GEMM core (64x512 tile, 2-barrier K-step,
// 2 blocks/CU) is the proven optimum for phase-1; scheduling variants all
// regressed (barriers drain vmcnt -> register-B dies; 1 block/CU -> no
// latency hiding). This round keeps that core and changes DATAFLOW:
//  * conv GEMM and pre GEMM fused into ONE kernel per 64-row tile. The pre
//    GEMM's A-rows are exactly the ce tile this block just computed -> keep
//    it in LDS (lT), phase-2 A needs NO staging and NO global ce re-read.
//  * phase-2 B (Wf, 512KB, L2-resident) goes global->register with a
//    one-slab-ahead prefetch in a BARRIER-FREE K-loop (nothing drains vmcnt
//    between issue and use — the round-6 bug).
//  * ce still written once to global (epilogue re-reads it L2-hot).
//  * prep+bias2+pe_tables+features merged into one launch; both small
//    GEMMs merged into one launch.  3 launches total.
// ---------------------------------------------------------------------------

typedef unsigned short u16;
using short8  = __attribute__((ext_vector_type(8))) short;
using floatx4 = __attribute__((ext_vector_type(4))) float;
typedef __attribute__((address_space(1))) const unsigned int u32_as1;
typedef __attribute__((address_space(3))) unsigned int       u32_as3;

static __device__ __forceinline__ u16 f2b(float f) {
  unsigned u = __float_as_uint(f);
  u += 0x7FFFu + ((u >> 16) & 1u);          // RNE
  return (u16)(u >> 16);
}
static __device__ __forceinline__ float b2f(u16 h) {
  return __uint_as_float(((unsigned)h) << 16);
}

// ------------------------------------------------- merged prep (one launch)
// blocks [0,12800): prep mats; [12800,12802): bias2; [12802,13826): pe
// tables; [13826,14850): rolling features.
__global__ __launch_bounds__(256) void prep_all(
    const float* __restrict__ x,
    const float* __restrict__ conv_w, const float* __restrict__ mixer_w,
    const float* __restrict__ tproj_w, const float* __restrict__ tape_pos,
    const float* __restrict__ tproj_b, const float* __restrict__ mixer_b,
    const float* __restrict__ learned_pe,
    const float* __restrict__ gf, const float* __restrict__ bf_,
    const float* __restrict__ gl, const float* __restrict__ bl,
    u16* __restrict__ W1, u16* __restrict__ A_m1, u16* __restrict__ M2t,
    u16* __restrict__ tprojT, u16* __restrict__ tape_bf,
    float* __restrict__ bias2, u16* __restrict__ pf_tab,
    u16* __restrict__ pl_tab, u16* __restrict__ comb) {
  __shared__ float sx[87 * 32];
  const int bx = blockIdx.x;
  if (bx < 12800) {
    int i = bx * 256 + threadIdx.x;
    if (i < 393216) {                                    // W1: 512*768
      int d = i / 768, rem = i - d * 768;
      int j = rem >> 8, c = rem & 255;
      W1[i] = f2b(conv_w[(d * 256 + c) * 3 + j]);
    } else if (i < 393216 + 262144) {
      int k = i - 393216; int p = k >> 9, r = k & 511;
      A_m1[k] = f2b(mixer_w[p * 1024 + r]);
    } else if (i < 393216 + 524288) {
      int k = i - 393216 - 262144; int p = k >> 9, r = k & 511;
      M2t[k] = f2b(mixer_w[p * 1024 + 512 + r]);
    } else if (i < 393216 + 786432) {
      int k = i - 393216 - 524288; int q = k >> 9, r = k & 511;
      tprojT[k] = f2b(tproj_w[r * 512 + q]);
    } else if (i < 393216 + 786432 + 2097152) {
      int k = i - 393216 - 786432;
      tape_bf[k] = f2b(tape_pos[k]);
    }
    return;
  }
  if (bx < 12802) {
    int p = (bx - 12800) * 256 + threadIdx.x;
    if (p < 512) {
      float s = mixer_b[p];
      for (int r = 0; r < 512; ++r) s += mixer_w[p * 1024 + r] * tproj_b[r];
      bias2[p] = s;
    }
    return;
  }
  if (bx < 13826) {
    // pe tables
    int row = (bx - 12802) * 4 + (threadIdx.x >> 6);
    int lane = threadIdx.x & 63;
    size_t base = (size_t)row * 512 + lane * 8;
    float v[8]; float s1 = 0.f, s2 = 0.f;
    #pragma unroll
    for (int e = 0; e < 8; ++e) {
      int d = lane * 8 + e;
      int de = d & ~1;
      float div = expf((float)de * (-9.210340371976184f / 512.f));
      float ang = (float)row * div;
      v[e] = (d & 1) ? cosf(ang) : sinf(ang);
      s1 += v[e]; s2 += v[e] * v[e];
    }
    #pragma unroll
    for (int off = 32; off; off >>= 1) { s1 += __shfl_xor(s1, off); s2 += __shfl_xor(s2, off); }
    float mean = s1 * (1.f / 512.f);
    float inv = rsqrtf(fmaxf(s2 * (1.f / 512.f) - mean * mean, 0.f) + 1e-5f);
    short8 o;
    #pragma unroll
    for (int e = 0; e < 8; ++e) {
      int d = lane * 8 + e;
      o[e] = (short)f2b(gf[d] * ((v[e] - mean) * inv) + bf_[d]);
    }
    *(short8*)(pf_tab + base) = o;
    const float4* lp = (const float4*)(learned_pe + base);
    float4 a = lp[0], bq = lp[1];
    float u[8] = {a.x, a.y, a.z, a.w, bq.x, bq.y, bq.z, bq.w};
    s1 = 0.f; s2 = 0.f;
    #pragma unroll
    for (int e = 0; e < 8; ++e) { s1 += u[e]; s2 += u[e] * u[e]; }
    #pragma unroll
    for (int off = 32; off; off >>= 1) { s1 += __shfl_xor(s1, off); s2 += __shfl_xor(s2, off); }
    mean = s1 * (1.f / 512.f);
    inv = rsqrtf(fmaxf(s2 * (1.f / 512.f) - mean * mean, 0.f) + 1e-5f);
    #pragma unroll
    for (int e = 0; e < 8; ++e) {
      int d = lane * 8 + e;
      o[e] = (short)f2b(gl[d] * ((u[e] - mean) * inv) + bl[d]);
    }
    *(short8*)(pl_tab + base) = o;
    return;
  }
  // ---- rolling features ----
  const int fb = bx - 13826;
  const int b = fb >> 6, l0 = (fb & 63) * 64;
  for (int idx = threadIdx.x; idx < 87 * 32; idx += 256) {
    int r = idx >> 5, c = idx & 31;
    int ls = l0 - 23 + r; if (ls < 0) ls = 0;
    sx[idx] = x[((size_t)b * 4096 + ls) * 32 + c];
  }
  __syncthreads();
  const int c = threadIdx.x & 31, lr0 = threadIdx.x >> 5;
  for (int pass = 0; pass < 8; ++pass) {
    int lr = pass * 8 + lr0;
    int l = l0 + lr;
    float w[24];
    float s = 0.f, mx = -3.4e38f, mn = 3.4e38f;
    #pragma unroll
    for (int i = 0; i < 24; ++i) {
      float v = sx[(lr + i) * 32 + c];
      w[i] = v; s += v; mx = fmaxf(mx, v); mn = fminf(mn, v);
    }
    float mean = s * (1.f / 24.f);
    float ssd = 0.f;
    #pragma unroll
    for (int i = 0; i < 24; ++i) { float d = w[i] - mean; ssd += d * d; }
    float sd = sqrtf(fmaxf(ssd, 0.f) * (1.f / 23.f));
    float xv = w[23];
    float lag3 = xv - sx[(lr + 20) * 32 + c];
    float lag5 = xv - sx[(lr + 18) * 32 + c];
    float lag7 = xv - sx[(lr + 16) * 32 + c];
    size_t base = ((size_t)b * 4096 + l) * 256 + c;
    comb[base +   0] = f2b(xv);
    comb[base +  32] = f2b(mean);
    comb[base +  64] = f2b(mx);
    comb[base +  96] = f2b(mn);
    comb[base + 128] = f2b(sd);
    comb[base + 160] = f2b(lag3);
    comb[base + 192] = f2b(lag5);
    comb[base + 224] = f2b(lag7);
  }
}

// ------------------------------------------------------- small bf16 GEMM
static __device__ __forceinline__ void gemm_bt_dev(
    const u16* __restrict__ A, const u16* __restrict__ Bt,
    u16* __restrict__ outp, int K, int ldc,
    const float* __restrict__ bias, int m0, int n0,
    u16* lA, u16* lB) {
  const int tid = threadIdx.x;
  const int wave = tid >> 6, lane = tid & 63;
  const int wm = (wave & 1) * 64, wn = (wave >> 1) * 64;
  const int quad = lane >> 4, r16 = lane & 15;
  const int rowT = tid >> 3, col8 = tid & 7;

  floatx4 acc[4][4];
  #pragma unroll
  for (int i = 0; i < 4; ++i)
    #pragma unroll
    for (int j = 0; j < 4; ++j) acc[i][j] = (floatx4){0.f, 0.f, 0.f, 0.f};

  for (int kk = 0; kk < K; kk += 64) {
    __syncthreads();
    #pragma unroll
    for (int it = 0; it < 4; ++it) {
      int rr = it * 32 + rowT;
      const u16* ga = A  + (size_t)(m0 + rr) * K + kk + col8 * 8;
      const u16* gb = Bt + (size_t)(n0 + rr) * K + kk + col8 * 8;
      __builtin_amdgcn_global_load_lds((u32_as1*)ga, (u32_as3*)&lA[rr * 64 + col8 * 8], 16, 0, 0);
      __builtin_amdgcn_global_load_lds((u32_as1*)gb, (u32_as3*)&lB[rr * 64 + col8 * 8], 16, 0, 0);
    }
    __syncthreads();
    #pragma unroll
    for (int ks = 0; ks < 64; ks += 32) {
      short8 af[4], bfr[4];
      #pragma unroll
      for (int i = 0; i < 4; ++i)
        af[i] = *(const short8*)&lA[(wm + i * 16 + r16) * 64 + ks + quad * 8];
      #pragma unroll
      for (int j = 0; j < 4; ++j)
        bfr[j] = *(const short8*)&lB[(wn + j * 16 + r16) * 64 + ks + quad * 8];
      #pragma unroll
      for (int i = 0; i < 4; ++i)
        #pragma unroll
        for (int j = 0; j < 4; ++j)
          acc[i][j] = __builtin_amdgcn_mfma_f32_16x16x32_bf16(af[i], bfr[j], acc[i][j], 0, 0, 0);
    }
  }
  #pragma unroll
  for (int i = 0; i < 4; ++i) {
    #pragma unroll
    for (int rr = 0; rr < 4; ++rr) {
      int m = m0 + wm + i * 16 + quad * 4 + rr;
      #pragma unroll
      for (int j = 0; j < 4; ++j) {
        int n = n0 + wn + j * 16 + r16;
        float v = acc[i][j][rr];
        if (bias) v += bias[n];
        outp[(size_t)m * ldc + n] = f2b(v);
      }
    }
  }
}

// blocks [0,16): Wf = M1 @ tprojT^T ; [16,144): ctab = tape @ M2t^T + bias2
__global__ __launch_bounds__(256) void gemm_bt_both(
    const u16* __restrict__ A_m1, const u16* __restrict__ tprojT,
    u16* __restrict__ Wf, const u16* __restrict__ tape_bf,
    const u16* __restrict__ M2t, u16* __restrict__ ctab_bf,
    const float* __restrict__ bias2) {
  __shared__ __align__(16) u16 lA[128 * 64];
  __shared__ __align__(16) u16 lB[128 * 64];
  const int bx = blockIdx.x;
  if (bx < 16) {
    gemm_bt_dev(A_m1, tprojT, Wf, 512, 512, nullptr,
                (bx & 3) * 128, (bx >> 2) * 128, lA, lB);
  } else {
    const int i = bx - 16;
    gemm_bt_dev(tape_bf, M2t, ctab_bf, 512, 512, bias2,
                (i & 31) * 128, (i >> 5) * 128, lA, lB);
  }
}

// ---------------------------------------------------------------------------
// Fused conv GEMM + LN + pre GEMM + LN + weighted sum.  Block = 64 m-rows x
// 512 n-cols, 256 threads (4 waves, wave w owns n-strip [w*128,w*128+128)).
// Operand-swapped MFMA: D = mfma(B_frag, A_frag):
//   lane(q,r): m = i*16 + r,  n = jj*16 + q*4 + rr
// Phase 1 (conv, K=768): round-3 proven: STAGE A(comb)+B(W1) -> LDS, 2
//   barriers per BK=64 step.  lA 8K @0, lB 64K @8192.
// Then: transpose+bias -> lT[64][520] (unions staging), LN -> ce global AND
//   normalized values written back into lT.
// Phase 2 (pre, K=512): A-frags read from lT (no staging); B = Wf rows in
//   registers, one-slab-ahead prefetch, NO barriers in the K-loop.
// Then: transpose pre -> lT, row-wise epilogue (LN(pre+ctab), weighted sum,
//   ce re-read from global = L2-hot).
// LDS: 73728 (staging/lT) + 4096 (g/b params, reloaded g_c->g_t mid-kernel)
// = 77824 <= 80K -> 2 blocks/CU.
// ---------------------------------------------------------------------------

#define STAGE_A(SRCEXPR)                                                       \
  _Pragma("unroll")                                                            \
  for (int it = 0; it < 2; ++it) {                                             \
    int id = it * 256 + tid, row = id >> 3, c = id & 7;                        \
    int cg = ((c ^ (row & 7)) << 3);                                           \
    const u16* gsrc = (SRCEXPR);                                               \
    __builtin_amdgcn_global_load_lds((u32_as1*)gsrc,                           \
        (u32_as3*)(smem + id * 16), 16, 0, 0);                                 \
  }
#define STAGE_B(SRCEXPR)                                                       \
  _Pragma("unroll")                                                            \
  for (int it = 0; it < 16; ++it) {                                            \
    int id = it * 256 + tid, row = id >> 3, c = id & 7;                        \
    int cg = ((c ^ (row & 7)) << 3);                                           \
    const u16* gsrc = (SRCEXPR);                                               \
    __builtin_amdgcn_global_load_lds((u32_as1*)gsrc,                           \
        (u32_as3*)(smem + 8192 + id * 16), 16, 0, 0);                          \
  }

__global__ __launch_bounds__(256, 2) void gemm_conv_pre(
    const u16* __restrict__ comb, const u16* __restrict__ W1,
    const float* __restrict__ conv_b, const float* __restrict__ g_c,
    const float* __restrict__ b_c, const u16* __restrict__ Wf,
    const u16* __restrict__ ctab_bf, const u16* __restrict__ pf_tab,
    const u16* __restrict__ pl_tab, const float* __restrict__ g_t,
    const float* __restrict__ b_t, const float* __restrict__ wp,
    u16* __restrict__ ce, float* __restrict__ out) {
  __shared__ __align__(16) char smem[73728];
  __shared__ __align__(16) float sGB[1024];     // [0,512)=gamma, [512,1024)=beta
  float* sG = sGB;
  float* sB = sGB + 512;
  u16* lA = (u16*)smem;
  u16* lB = (u16*)(smem + 8192);
  u16* lT = (u16*)smem;                         // [64][520]

  const int tid = threadIdx.x;
  if (tid < 128) {
    ((float4*)sG)[tid] = ((const float4*)g_c)[tid];
    ((float4*)sB)[tid] = ((const float4*)b_c)[tid];
  }
  const int m0 = blockIdx.x * 64;
  const int b = m0 >> 12, l0 = m0 & 4095;
  const int w = tid >> 6, lane = tid & 63;
  const int quad = lane >> 4, r16 = lane & 15;
  const int wn = w * 128;

  // ================= phase 1: conv GEMM (round-3 structure) ================
  floatx4 acc[4][8];
  #pragma unroll
  for (int i = 0; i < 4; ++i)
    #pragma unroll
    for (int jj = 0; jj < 8; ++jj) acc[i][jj] = (floatx4){0.f, 0.f, 0.f, 0.f};

  for (int kk = 0; kk < 768; kk += 64) {
    const int jsh = kk >> 8, kc = kk & 255;
    __syncthreads();
    STAGE_A(comb + (((size_t)b * 4096 + ((l0 + row + jsh - 1 + 4096) & 4095)) << 8) + kc + cg)
    STAGE_B(W1 + (size_t)row * 768 + kk + cg)
    __syncthreads();
    #pragma unroll
    for (int ks = 0; ks < 64; ks += 32) {
      short8 af[4];
      #pragma unroll
      for (int i = 0; i < 4; ++i) {
        int row = i * 16 + r16;
        af[i] = *(const short8*)&lA[row * 64 + ((((ks >> 3) + quad) ^ (row & 7)) << 3)];
      }
      #pragma unroll
      for (int jj = 0; jj < 8; ++jj) {
        int row = wn + jj * 16 + r16;
        short8 bf = *(const short8*)&lB[row * 64 + ((((ks >> 3) + quad) ^ (row & 7)) << 3)];
        #pragma unroll
        for (int i = 0; i < 4; ++i)
          acc[i][jj] = __builtin_amdgcn_mfma_f32_16x16x32_bf16(bf, af[i], acc[i][jj], 0, 0, 0);
      }
    }
  }
  __syncthreads();
  // transpose to lT with conv bias added (pre-LN); bias read from global (L2)
  #pragma unroll
  for (int jj = 0; jj < 8; ++jj) {
    int n = wn + jj * 16 + quad * 4;
    float4 b4 = *(const float4*)&conv_b[n];
    #pragma unroll
    for (int i = 0; i < 4; ++i) {
      ushort4 pk;
      pk.x = f2b(acc[i][jj][0] + b4.x);
      pk.y = f2b(acc[i][jj][1] + b4.y);
      pk.z = f2b(acc[i][jj][2] + b4.z);
      pk.w = f2b(acc[i][jj][3] + b4.w);
      *(ushort4*)(lT + (size_t)(i * 16 + r16) * 520 + n) = pk;
    }
  }
  __syncthreads();
  // conv LN: write ce to global AND normalized values back into lT
  {
    const int orow = tid >> 2, part = tid & 3;
    u16* rowp = lT + (size_t)orow * 520;
    float s1 = 0.f, s2 = 0.f;
    #pragma unroll
    for (int k = 0; k < 16; ++k) {
      short8 t8 = *(const short8*)(rowp + (part + k * 4) * 8);
      #pragma unroll
      for (int e = 0; e < 8; ++e) {
        float f = b2f((u16)t8[e]); s1 += f; s2 += f * f;
      }
    }
    s1 += __shfl_xor(s1, 1); s2 += __shfl_xor(s2, 1);
    s1 += __shfl_xor(s1, 2); s2 += __shfl_xor(s2, 2);
    float mean = s1 * (1.f / 512.f);
    float inv = rsqrtf(fmaxf(s2 * (1.f / 512.f) - mean * mean, 0.f) + 1e-5f);
    size_t mrow = (size_t)(m0 + orow) * 512;
    #pragma unroll
    for (int k = 0; k < 16; ++k) {
      int c8 = part + k * 4;
      short8 t8 = *(const short8*)(rowp + c8 * 8);
      short8 o;
      #pragma unroll
      for (int e = 0; e < 8; ++e) {
        int d = c8 * 8 + e;
        o[e] = (short)f2b(sG[d] * ((b2f((u16)t8[e]) - mean) * inv) + sB[d]);
      }
      *(short8*)(ce + mrow + c8 * 8) = o;          // global (epilogue re-reads, L2-hot)
      *(short8*)(rowp + c8 * 8) = o;               // back into lT (phase-2 A operand)
    }
  }
  __syncthreads();
  // reload gamma/beta with the tAPE LN params (epilogue use)
  if (tid < 128) {
    ((float4*)sG)[tid] = ((const float4*)g_t)[tid];
    ((float4*)sB)[tid] = ((const float4*)b_t)[tid];
  }

  // ============ phase 2: pre GEMM — A from lT, B in regs, NO barriers ======
  floatx4 acc2[4][8];
  #pragma unroll
  for (int i = 0; i < 4; ++i)
    #pragma unroll
    for (int jj = 0; jj < 8; ++jj) acc2[i][jj] = (floatx4){0.f, 0.f, 0.f, 0.f};

  const u16* bw2 = Wf + (size_t)(wn + r16) * 512 + quad * 8;
  short8 bf2[8], bfN[8];
  #pragma unroll
  for (int jj = 0; jj < 8; ++jj)
    bf2[jj] = *(const short8*)(bw2 + (size_t)jj * 8192);
  #pragma unroll 1
  for (int u = 0; u < 16; ++u) {                   // 16 slabs of K=32
    if (u < 15) {
      #pragma unroll
      for (int jj = 0; jj < 8; ++jj)
        bfN[jj] = *(const short8*)(bw2 + (size_t)jj * 8192 + (u + 1) * 32);
    }
    short8 af[4];
    #pragma unroll
    for (int i = 0; i < 4; ++i)
      af[i] = *(const short8*)(lT + (size_t)(i * 16 + r16) * 520 + u * 32 + quad * 8);
    __builtin_amdgcn_s_setprio(1);
    #pragma unroll
    for (int jj = 0; jj < 8; ++jj)
      #pragma unroll
      for (int i = 0; i < 4; ++i)
        acc2[i][jj] = __builtin_amdgcn_mfma_f32_16x16x32_bf16(bf2[jj], af[i], acc2[i][jj], 0, 0, 0);
    __builtin_amdgcn_s_setprio(0);
    #pragma unroll
    for (int jj = 0; jj < 8; ++jj) bf2[jj] = bfN[jj];
  }
  __syncthreads();                                  // all lT reads done
  // transpose pre -> lT (overwrites normalized ce; global copy remains)
  #pragma unroll
  for (int jj = 0; jj < 8; ++jj) {
    int n = wn + jj * 16 + quad * 4;
    #pragma unroll
    for (int i = 0; i < 4; ++i) {
      ushort4 pk;
      pk.x = f2b(acc2[i][jj][0]);
      pk.y = f2b(acc2[i][jj][1]);
      pk.z = f2b(acc2[i][jj][2]);
      pk.w = f2b(acc2[i][jj][3]);
      *(ushort4*)(lT + (size_t)(i * 16 + r16) * 520 + n) = pk;
    }
  }
  __syncthreads();
  // =============== epilogue: LN(pre+ctab) + weighted sum -> out ============
  const int orow = tid >> 2, part = tid & 3;
  const int m = m0 + orow, l = l0 + orow;
  const u16* rowp = lT + (size_t)orow * 520;
  const size_t lrow = (size_t)l * 512, mrow = (size_t)m * 512;
  float s1 = 0.f, s2 = 0.f;
  #pragma unroll
  for (int k = 0; k < 16; ++k) {
    int c8 = part + k * 4;
    short8 t8 = *(const short8*)(rowp + c8 * 8);
    short8 ct = *(const short8*)(ctab_bf + lrow + c8 * 8);
    #pragma unroll
    for (int e = 0; e < 8; ++e) {
      float f = b2f((u16)t8[e]) + b2f((u16)ct[e]);
      s1 += f; s2 += f * f;
    }
  }
  s1 += __shfl_xor(s1, 1); s2 += __shfl_xor(s2, 1);
  s1 += __shfl_xor(s1, 2); s2 += __shfl_xor(s2, 2);
  float mean = s1 * (1.f / 512.f);
  float inv = rsqrtf(fmaxf(s2 * (1.f / 512.f) - mean * mean, 0.f) + 1e-5f);

  float a0 = wp[0], a1 = wp[1], a2 = wp[2], a3 = wp[3];
  float mxw = fmaxf(fmaxf(a0, a1), fmaxf(a2, a3));
  float e0 = expf(a0 - mxw), e1 = expf(a1 - mxw), e2 = expf(a2 - mxw), e3 = expf(a3 - mxw);
  float invs = 1.f / (e0 + e1 + e2 + e3);
  float w0 = e0 * invs, w1 = e1 * invs, w2 = e2 * invs, w3 = e3 * invs;

  #pragma unroll
  for (int k = 0; k < 16; ++k) {
    int c8 = part + k * 4;
    short8 t8  = *(const short8*)(rowp + c8 * 8);
    short8 ct  = *(const short8*)(ctab_bf + lrow + c8 * 8);
    short8 c8v = *(const short8*)(ce + mrow + c8 * 8);
    short8 pf  = *(const short8*)(pf_tab + lrow + c8 * 8);
    short8 pl  = *(const short8*)(pl_tab + lrow + c8 * 8);
    float o[8];
    #pragma unroll
    for (int e = 0; e < 8; ++e) {
      int d = c8 * 8 + e;
      float f = b2f((u16)t8[e]) + b2f((u16)ct[e]);
      float pt = sG[d] * ((f - mean) * inv) + sB[d];
      o[e] = w0 * b2f((u16)c8v[e]) + w1 * b2f((u16)pf[e]) + w2 * b2f((u16)pl[e]) + w3 * pt;
    }
    float4* op = (float4*)(out + mrow + c8 * 8);
    op[0] = make_float4(o[0], o[1], o[2], o[3]);
    op[1] = make_float4(o[4], o[5], o[6], o[7]);
  }
}

// ---------------------------------------------------------------------------
extern "C" void kernel_launch(void* const* d_in, const int* in_sizes, int n_in,
                              void* d_out, int out_size, void* d_ws, size_t ws_size,
                              hipStream_t stream) {
  const float* x          = (const float*)d_in[0];
  const float* conv_w     = (const float*)d_in[1];
  const float* conv_b     = (const float*)d_in[2];
  const float* learned_pe = (const float*)d_in[3];
  const float* tape_pos   = (const float*)d_in[4];
  const float* tproj_w    = (const float*)d_in[5];
  const float* tproj_b    = (const float*)d_in[6];
  const float* mixer_w    = (const float*)d_in[7];
  const float* mixer_b    = (const float*)d_in[8];
  const float* g_c        = (const float*)d_in[9];
  const float* b_c        = (const float*)d_in[10];
  const float* g_f        = (const float*)d_in[11];
  const float* b_f        = (const float*)d_in[12];
  const float* g_l        = (const float*)d_in[13];
  const float* b_l        = (const float*)d_in[14];
  const float* g_t        = (const float*)d_in[15];
  const float* b_t        = (const float*)d_in[16];
  const float* wp         = (const float*)d_in[17];

  char* ws = (char*)d_ws;
  u16*  comb    = (u16*)(ws + 0);             // 32 MiB
  u16*  ce      = (u16*)(ws + 33554432);      // 64 MiB
  char* S       = ws + 100663296;
  u16*  W1      = (u16*)(S + 0);              // 768 KiB
  u16*  A_m1    = (u16*)(S + 786432);         // 512 KiB
  u16*  M2t     = (u16*)(S + 1310720);        // 512 KiB
  u16*  tprojT  = (u16*)(S + 1835008);        // 512 KiB
  u16*  tape_bf = (u16*)(S + 2359296);        // 4 MiB
  u16*  Wf      = (u16*)(S + 6553600);        // 512 KiB
  u16*  ctab_bf = (u16*)(S + 7077888);        // 4 MiB
  float* bias2  = (float*)(S + 11272192);     // 2 KiB
  u16*  pf_tab  = (u16*)(S + 11274240);       // 4 MiB
  u16*  pl_tab  = (u16*)(S + 15468544);       // 4 MiB

  // 1) all precompute + features in one launch
  prep_all<<<14850, 256, 0, stream>>>(x, conv_w, mixer_w, tproj_w, tape_pos,
                                      tproj_b, mixer_b, learned_pe,
                                      g_f, b_f, g_l, b_l,
                                      W1, A_m1, M2t, tprojT, tape_bf,
                                      bias2, pf_tab, pl_tab, comb);
  // 2) both small GEMMs (Wf, ctab) in one launch
  gemm_bt_both<<<144, 256, 0, stream>>>(A_m1, tprojT, Wf, tape_bf, M2t,
                                        ctab_bf, bias2);
  // 3) fused conv GEMM + LN + pre GEMM + LN + weighted sum
  gemm_conv_pre<<<1024, 256, 0, stream>>>(comb, W1, conv_b, g_c, b_c,
                                          Wf, ctab_bf, pf_tab, pl_tab,
                                          g_t, b_t, wp, ce, (float*)d_out);
}

// Round 5
// 355.996 us; speedup vs baseline: 1.2566x; 1.0897x over previous
//
#include <hip/hip_runtime.h>
#include <stdint.h>

// ---------------------------------------------------------------------------
// DataEmbedding_ALLPE_Weighted on MI355X (gfx950)  — round 8
//
// Round-7 post-mortem: fused kernel = 239 us ~= conv(97) + phase2(142); the
// barrier-free register-B phase-2 loop is 1.6x SLOWER than the proven DMA
// 2-barrier structure (per-iter vmcnt drain of 8 L2 loads with only ~160cy
// of MFMA cover + 32 v_movs, at 2 waves/SIMD). Bank conflicts measured
// negligible (~3% of cycles). Rule confirmed 3x: only DMA + 2-barrier +
// 2 blocks/CU performs here. Round 8 = fusion-lite: keep the single fused
// kernel (launch savings + ce stays L2-local to the writing XCD), but run
// BOTH phases with the proven round-3 K-loop: phase 2 stages A from ce
// global (8KB/step, L2-hot, same block wrote it) and B from Wf via
// global_load_lds, 2 barriers per BK=64 step.
// ---------------------------------------------------------------------------

typedef unsigned short u16;
using short8  = __attribute__((ext_vector_type(8))) short;
using floatx4 = __attribute__((ext_vector_type(4))) float;
typedef __attribute__((address_space(1))) const unsigned int u32_as1;
typedef __attribute__((address_space(3))) unsigned int       u32_as3;

static __device__ __forceinline__ u16 f2b(float f) {
  unsigned u = __float_as_uint(f);
  u += 0x7FFFu + ((u >> 16) & 1u);          // RNE
  return (u16)(u >> 16);
}
static __device__ __forceinline__ float b2f(u16 h) {
  return __uint_as_float(((unsigned)h) << 16);
}

// ------------------------------------------------- merged prep (one launch)
// blocks [0,12800): prep mats; [12800,12802): bias2; [12802,13826): pe
// tables; [13826,14850): rolling features.
__global__ __launch_bounds__(256) void prep_all(
    const float* __restrict__ x,
    const float* __restrict__ conv_w, const float* __restrict__ mixer_w,
    const float* __restrict__ tproj_w, const float* __restrict__ tape_pos,
    const float* __restrict__ tproj_b, const float* __restrict__ mixer_b,
    const float* __restrict__ learned_pe,
    const float* __restrict__ gf, const float* __restrict__ bf_,
    const float* __restrict__ gl, const float* __restrict__ bl,
    u16* __restrict__ W1, u16* __restrict__ A_m1, u16* __restrict__ M2t,
    u16* __restrict__ tprojT, u16* __restrict__ tape_bf,
    float* __restrict__ bias2, u16* __restrict__ pf_tab,
    u16* __restrict__ pl_tab, u16* __restrict__ comb) {
  __shared__ float sx[87 * 32];
  const int bx = blockIdx.x;
  if (bx < 12800) {
    int i = bx * 256 + threadIdx.x;
    if (i < 393216) {                                    // W1: 512*768
      int d = i / 768, rem = i - d * 768;
      int j = rem >> 8, c = rem & 255;
      W1[i] = f2b(conv_w[(d * 256 + c) * 3 + j]);
    } else if (i < 393216 + 262144) {
      int k = i - 393216; int p = k >> 9, r = k & 511;
      A_m1[k] = f2b(mixer_w[p * 1024 + r]);
    } else if (i < 393216 + 524288) {
      int k = i - 393216 - 262144; int p = k >> 9, r = k & 511;
      M2t[k] = f2b(mixer_w[p * 1024 + 512 + r]);
    } else if (i < 393216 + 786432) {
      int k = i - 393216 - 524288; int q = k >> 9, r = k & 511;
      tprojT[k] = f2b(tproj_w[r * 512 + q]);
    } else if (i < 393216 + 786432 + 2097152) {
      int k = i - 393216 - 786432;
      tape_bf[k] = f2b(tape_pos[k]);
    }
    return;
  }
  if (bx < 12802) {
    int p = (bx - 12800) * 256 + threadIdx.x;
    if (p < 512) {
      float s = mixer_b[p];
      for (int r = 0; r < 512; ++r) s += mixer_w[p * 1024 + r] * tproj_b[r];
      bias2[p] = s;
    }
    return;
  }
  if (bx < 13826) {
    // pe tables
    int row = (bx - 12802) * 4 + (threadIdx.x >> 6);
    int lane = threadIdx.x & 63;
    size_t base = (size_t)row * 512 + lane * 8;
    float v[8]; float s1 = 0.f, s2 = 0.f;
    #pragma unroll
    for (int e = 0; e < 8; ++e) {
      int d = lane * 8 + e;
      int de = d & ~1;
      float div = expf((float)de * (-9.210340371976184f / 512.f));
      float ang = (float)row * div;
      v[e] = (d & 1) ? cosf(ang) : sinf(ang);
      s1 += v[e]; s2 += v[e] * v[e];
    }
    #pragma unroll
    for (int off = 32; off; off >>= 1) { s1 += __shfl_xor(s1, off); s2 += __shfl_xor(s2, off); }
    float mean = s1 * (1.f / 512.f);
    float inv = rsqrtf(fmaxf(s2 * (1.f / 512.f) - mean * mean, 0.f) + 1e-5f);
    short8 o;
    #pragma unroll
    for (int e = 0; e < 8; ++e) {
      int d = lane * 8 + e;
      o[e] = (short)f2b(gf[d] * ((v[e] - mean) * inv) + bf_[d]);
    }
    *(short8*)(pf_tab + base) = o;
    const float4* lp = (const float4*)(learned_pe + base);
    float4 a = lp[0], bq = lp[1];
    float u[8] = {a.x, a.y, a.z, a.w, bq.x, bq.y, bq.z, bq.w};
    s1 = 0.f; s2 = 0.f;
    #pragma unroll
    for (int e = 0; e < 8; ++e) { s1 += u[e]; s2 += u[e] * u[e]; }
    #pragma unroll
    for (int off = 32; off; off >>= 1) { s1 += __shfl_xor(s1, off); s2 += __shfl_xor(s2, off); }
    mean = s1 * (1.f / 512.f);
    inv = rsqrtf(fmaxf(s2 * (1.f / 512.f) - mean * mean, 0.f) + 1e-5f);
    #pragma unroll
    for (int e = 0; e < 8; ++e) {
      int d = lane * 8 + e;
      o[e] = (short)f2b(gl[d] * ((u[e] - mean) * inv) + bl[d]);
    }
    *(short8*)(pl_tab + base) = o;
    return;
  }
  // ---- rolling features ----
  const int fb = bx - 13826;
  const int b = fb >> 6, l0 = (fb & 63) * 64;
  for (int idx = threadIdx.x; idx < 87 * 32; idx += 256) {
    int r = idx >> 5, c = idx & 31;
    int ls = l0 - 23 + r; if (ls < 0) ls = 0;
    sx[idx] = x[((size_t)b * 4096 + ls) * 32 + c];
  }
  __syncthreads();
  const int c = threadIdx.x & 31, lr0 = threadIdx.x >> 5;
  for (int pass = 0; pass < 8; ++pass) {
    int lr = pass * 8 + lr0;
    int l = l0 + lr;
    float w[24];
    float s = 0.f, mx = -3.4e38f, mn = 3.4e38f;
    #pragma unroll
    for (int i = 0; i < 24; ++i) {
      float v = sx[(lr + i) * 32 + c];
      w[i] = v; s += v; mx = fmaxf(mx, v); mn = fminf(mn, v);
    }
    float mean = s * (1.f / 24.f);
    float ssd = 0.f;
    #pragma unroll
    for (int i = 0; i < 24; ++i) { float d = w[i] - mean; ssd += d * d; }
    float sd = sqrtf(fmaxf(ssd, 0.f) * (1.f / 23.f));
    float xv = w[23];
    float lag3 = xv - sx[(lr + 20) * 32 + c];
    float lag5 = xv - sx[(lr + 18) * 32 + c];
    float lag7 = xv - sx[(lr + 16) * 32 + c];
    size_t base = ((size_t)b * 4096 + l) * 256 + c;
    comb[base +   0] = f2b(xv);
    comb[base +  32] = f2b(mean);
    comb[base +  64] = f2b(mx);
    comb[base +  96] = f2b(mn);
    comb[base + 128] = f2b(sd);
    comb[base + 160] = f2b(lag3);
    comb[base + 192] = f2b(lag5);
    comb[base + 224] = f2b(lag7);
  }
}

// ------------------------------------------------------- small bf16 GEMM
static __device__ __forceinline__ void gemm_bt_dev(
    const u16* __restrict__ A, const u16* __restrict__ Bt,
    u16* __restrict__ outp, int K, int ldc,
    const float* __restrict__ bias, int m0, int n0,
    u16* lA, u16* lB) {
  const int tid = threadIdx.x;
  const int wave = tid >> 6, lane = tid & 63;
  const int wm = (wave & 1) * 64, wn = (wave >> 1) * 64;
  const int quad = lane >> 4, r16 = lane & 15;
  const int rowT = tid >> 3, col8 = tid & 7;

  floatx4 acc[4][4];
  #pragma unroll
  for (int i = 0; i < 4; ++i)
    #pragma unroll
    for (int j = 0; j < 4; ++j) acc[i][j] = (floatx4){0.f, 0.f, 0.f, 0.f};

  for (int kk = 0; kk < K; kk += 64) {
    __syncthreads();
    #pragma unroll
    for (int it = 0; it < 4; ++it) {
      int rr = it * 32 + rowT;
      const u16* ga = A  + (size_t)(m0 + rr) * K + kk + col8 * 8;
      const u16* gb = Bt + (size_t)(n0 + rr) * K + kk + col8 * 8;
      __builtin_amdgcn_global_load_lds((u32_as1*)ga, (u32_as3*)&lA[rr * 64 + col8 * 8], 16, 0, 0);
      __builtin_amdgcn_global_load_lds((u32_as1*)gb, (u32_as3*)&lB[rr * 64 + col8 * 8], 16, 0, 0);
    }
    __syncthreads();
    #pragma unroll
    for (int ks = 0; ks < 64; ks += 32) {
      short8 af[4], bfr[4];
      #pragma unroll
      for (int i = 0; i < 4; ++i)
        af[i] = *(const short8*)&lA[(wm + i * 16 + r16) * 64 + ks + quad * 8];
      #pragma unroll
      for (int j = 0; j < 4; ++j)
        bfr[j] = *(const short8*)&lB[(wn + j * 16 + r16) * 64 + ks + quad * 8];
      #pragma unroll
      for (int i = 0; i < 4; ++i)
        #pragma unroll
        for (int j = 0; j < 4; ++j)
          acc[i][j] = __builtin_amdgcn_mfma_f32_16x16x32_bf16(af[i], bfr[j], acc[i][j], 0, 0, 0);
    }
  }
  #pragma unroll
  for (int i = 0; i < 4; ++i) {
    #pragma unroll
    for (int rr = 0; rr < 4; ++rr) {
      int m = m0 + wm + i * 16 + quad * 4 + rr;
      #pragma unroll
      for (int j = 0; j < 4; ++j) {
        int n = n0 + wn + j * 16 + r16;
        float v = acc[i][j][rr];
        if (bias) v += bias[n];
        outp[(size_t)m * ldc + n] = f2b(v);
      }
    }
  }
}

// blocks [0,16): Wf = M1 @ tprojT^T ; [16,144): ctab = tape @ M2t^T + bias2
__global__ __launch_bounds__(256) void gemm_bt_both(
    const u16* __restrict__ A_m1, const u16* __restrict__ tprojT,
    u16* __restrict__ Wf, const u16* __restrict__ tape_bf,
    const u16* __restrict__ M2t, u16* __restrict__ ctab_bf,
    const float* __restrict__ bias2) {
  __shared__ __align__(16) u16 lA[128 * 64];
  __shared__ __align__(16) u16 lB[128 * 64];
  const int bx = blockIdx.x;
  if (bx < 16) {
    gemm_bt_dev(A_m1, tprojT, Wf, 512, 512, nullptr,
                (bx & 3) * 128, (bx >> 2) * 128, lA, lB);
  } else {
    const int i = bx - 16;
    gemm_bt_dev(tape_bf, M2t, ctab_bf, 512, 512, bias2,
                (i & 31) * 128, (i >> 5) * 128, lA, lB);
  }
}

// ---------------------------------------------------------------------------
// Fused conv GEMM + LN + pre GEMM + LN + weighted sum.  Block = 64 m-rows x
// 512 n-cols, 256 threads (4 waves, wave w owns n-strip [w*128,w*128+128)).
// Operand-swapped MFMA: D = mfma(B_frag, A_frag):
//   lane(q,r): m = i*16 + r,  n = jj*16 + q*4 + rr
// BOTH phases use the proven round-3 K-loop: STAGE A+B via global_load_lds,
// 2 barriers per BK=64 step, XOR chunk swizzle c^(row&7).
//   Phase 1 (conv, K=768): A = comb (circular row shift), B = W1.
//   Phase 2 (pre,  K=512): A = ce (just written by THIS block -> same-XCD
//     L2 hit; loop-top __syncthreads drains the stores first), B = Wf.
// Epilogues transpose acc -> lT[64][520] (unions staging) and do row-wise
// two-pass LN over LDS. 3 launches total for the whole pipeline.
// LDS: 73728 staging/lT + 4096 params = 77824 <= 80K -> 2 blocks/CU.
// ---------------------------------------------------------------------------

#define STAGE_A(SRCEXPR)                                                       \
  _Pragma("unroll")                                                            \
  for (int it = 0; it < 2; ++it) {                                             \
    int id = it * 256 + tid, row = id >> 3, c = id & 7;                        \
    int cg = ((c ^ (row & 7)) << 3);                                           \
    const u16* gsrc = (SRCEXPR);                                               \
    __builtin_amdgcn_global_load_lds((u32_as1*)gsrc,                           \
        (u32_as3*)(smem + id * 16), 16, 0, 0);                                 \
  }
#define STAGE_B(SRCEXPR)                                                       \
  _Pragma("unroll")                                                            \
  for (int it = 0; it < 16; ++it) {                                            \
    int id = it * 256 + tid, row = id >> 3, c = id & 7;                        \
    int cg = ((c ^ (row & 7)) << 3);                                           \
    const u16* gsrc = (SRCEXPR);                                               \
    __builtin_amdgcn_global_load_lds((u32_as1*)gsrc,                           \
        (u32_as3*)(smem + 8192 + id * 16), 16, 0, 0);                          \
  }

__global__ __launch_bounds__(256, 2) void gemm_conv_pre(
    const u16* __restrict__ comb, const u16* __restrict__ W1,
    const float* __restrict__ conv_b, const float* __restrict__ g_c,
    const float* __restrict__ b_c, const u16* __restrict__ Wf,
    const u16* __restrict__ ctab_bf, const u16* __restrict__ pf_tab,
    const u16* __restrict__ pl_tab, const float* __restrict__ g_t,
    const float* __restrict__ b_t, const float* __restrict__ wp,
    u16* __restrict__ ce, float* __restrict__ out) {
  __shared__ __align__(16) char smem[73728];
  __shared__ __align__(16) float sGB[1024];     // [0,512)=gamma, [512,1024)=beta
  float* sG = sGB;
  float* sB = sGB + 512;
  u16* lA = (u16*)smem;
  u16* lB = (u16*)(smem + 8192);
  u16* lT = (u16*)smem;                         // [64][520]

  const int tid = threadIdx.x;
  if (tid < 128) {
    ((float4*)sG)[tid] = ((const float4*)g_c)[tid];
    ((float4*)sB)[tid] = ((const float4*)b_c)[tid];
  }
  const int m0 = blockIdx.x * 64;
  const int b = m0 >> 12, l0 = m0 & 4095;
  const int w = tid >> 6, lane = tid & 63;
  const int quad = lane >> 4, r16 = lane & 15;
  const int wn = w * 128;

  // ================= phase 1: conv GEMM (proven structure) =================
  floatx4 acc[4][8];
  #pragma unroll
  for (int i = 0; i < 4; ++i)
    #pragma unroll
    for (int jj = 0; jj < 8; ++jj) acc[i][jj] = (floatx4){0.f, 0.f, 0.f, 0.f};

  for (int kk = 0; kk < 768; kk += 64) {
    const int jsh = kk >> 8, kc = kk & 255;
    __syncthreads();
    STAGE_A(comb + (((size_t)b * 4096 + ((l0 + row + jsh - 1 + 4096) & 4095)) << 8) + kc + cg)
    STAGE_B(W1 + (size_t)row * 768 + kk + cg)
    __syncthreads();
    #pragma unroll
    for (int ks = 0; ks < 64; ks += 32) {
      short8 af[4];
      #pragma unroll
      for (int i = 0; i < 4; ++i) {
        int row = i * 16 + r16;
        af[i] = *(const short8*)&lA[row * 64 + ((((ks >> 3) + quad) ^ (row & 7)) << 3)];
      }
      #pragma unroll
      for (int jj = 0; jj < 8; ++jj) {
        int row = wn + jj * 16 + r16;
        short8 bf = *(const short8*)&lB[row * 64 + ((((ks >> 3) + quad) ^ (row & 7)) << 3)];
        #pragma unroll
        for (int i = 0; i < 4; ++i)
          acc[i][jj] = __builtin_amdgcn_mfma_f32_16x16x32_bf16(bf, af[i], acc[i][jj], 0, 0, 0);
      }
    }
  }
  __syncthreads();
  // transpose to lT with conv bias added (pre-LN); bias read from global (L2)
  #pragma unroll
  for (int jj = 0; jj < 8; ++jj) {
    int n = wn + jj * 16 + quad * 4;
    float4 b4 = *(const float4*)&conv_b[n];
    #pragma unroll
    for (int i = 0; i < 4; ++i) {
      ushort4 pk;
      pk.x = f2b(acc[i][jj][0] + b4.x);
      pk.y = f2b(acc[i][jj][1] + b4.y);
      pk.z = f2b(acc[i][jj][2] + b4.z);
      pk.w = f2b(acc[i][jj][3] + b4.w);
      *(ushort4*)(lT + (size_t)(i * 16 + r16) * 520 + n) = pk;
    }
  }
  __syncthreads();
  // conv LN: write normalized ce to global (re-staged L2-hot in phase 2)
  {
    const int orow = tid >> 2, part = tid & 3;
    u16* rowp = lT + (size_t)orow * 520;
    float s1 = 0.f, s2 = 0.f;
    #pragma unroll
    for (int k = 0; k < 16; ++k) {
      short8 t8 = *(const short8*)(rowp + (part + k * 4) * 8);
      #pragma unroll
      for (int e = 0; e < 8; ++e) {
        float f = b2f((u16)t8[e]); s1 += f; s2 += f * f;
      }
    }
    s1 += __shfl_xor(s1, 1); s2 += __shfl_xor(s2, 1);
    s1 += __shfl_xor(s1, 2); s2 += __shfl_xor(s2, 2);
    float mean = s1 * (1.f / 512.f);
    float inv = rsqrtf(fmaxf(s2 * (1.f / 512.f) - mean * mean, 0.f) + 1e-5f);
    size_t mrow = (size_t)(m0 + orow) * 512;
    #pragma unroll
    for (int k = 0; k < 16; ++k) {
      int c8 = part + k * 4;
      short8 t8 = *(const short8*)(rowp + c8 * 8);
      short8 o;
      #pragma unroll
      for (int e = 0; e < 8; ++e) {
        int d = c8 * 8 + e;
        o[e] = (short)f2b(sG[d] * ((b2f((u16)t8[e]) - mean) * inv) + sB[d]);
      }
      *(short8*)(ce + mrow + c8 * 8) = o;
    }
  }
  __syncthreads();
  // reload gamma/beta with the tAPE LN params (epilogue use)
  if (tid < 128) {
    ((float4*)sG)[tid] = ((const float4*)g_t)[tid];
    ((float4*)sB)[tid] = ((const float4*)b_t)[tid];
  }

  // ===== phase 2: pre GEMM — proven staged structure, A = ce (L2-hot) =====
  floatx4 acc2[4][8];
  #pragma unroll
  for (int i = 0; i < 4; ++i)
    #pragma unroll
    for (int jj = 0; jj < 8; ++jj) acc2[i][jj] = (floatx4){0.f, 0.f, 0.f, 0.f};

  for (int kk = 0; kk < 512; kk += 64) {
    __syncthreads();   // first iter: also guarantees ce stores drained (vmcnt0)
    STAGE_A(ce + (size_t)(m0 + row) * 512 + kk + cg)
    STAGE_B(Wf + (size_t)row * 512 + kk + cg)
    __syncthreads();
    #pragma unroll
    for (int ks = 0; ks < 64; ks += 32) {
      short8 af[4];
      #pragma unroll
      for (int i = 0; i < 4; ++i) {
        int row = i * 16 + r16;
        af[i] = *(const short8*)&lA[row * 64 + ((((ks >> 3) + quad) ^ (row & 7)) << 3)];
      }
      #pragma unroll
      for (int jj = 0; jj < 8; ++jj) {
        int row = wn + jj * 16 + r16;
        short8 bf = *(const short8*)&lB[row * 64 + ((((ks >> 3) + quad) ^ (row & 7)) << 3)];
        #pragma unroll
        for (int i = 0; i < 4; ++i)
          acc2[i][jj] = __builtin_amdgcn_mfma_f32_16x16x32_bf16(bf, af[i], acc2[i][jj], 0, 0, 0);
      }
    }
  }
  __syncthreads();
  // transpose pre -> lT
  #pragma unroll
  for (int jj = 0; jj < 8; ++jj) {
    int n = wn + jj * 16 + quad * 4;
    #pragma unroll
    for (int i = 0; i < 4; ++i) {
      ushort4 pk;
      pk.x = f2b(acc2[i][jj][0]);
      pk.y = f2b(acc2[i][jj][1]);
      pk.z = f2b(acc2[i][jj][2]);
      pk.w = f2b(acc2[i][jj][3]);
      *(ushort4*)(lT + (size_t)(i * 16 + r16) * 520 + n) = pk;
    }
  }
  __syncthreads();
  // =============== epilogue: LN(pre+ctab) + weighted sum -> out ============
  const int orow = tid >> 2, part = tid & 3;
  const int m = m0 + orow, l = l0 + orow;
  const u16* rowp = lT + (size_t)orow * 520;
  const size_t lrow = (size_t)l * 512, mrow = (size_t)m * 512;
  float s1 = 0.f, s2 = 0.f;
  #pragma unroll
  for (int k = 0; k < 16; ++k) {
    int c8 = part + k * 4;
    short8 t8 = *(const short8*)(rowp + c8 * 8);
    short8 ct = *(const short8*)(ctab_bf + lrow + c8 * 8);
    #pragma unroll
    for (int e = 0; e < 8; ++e) {
      float f = b2f((u16)t8[e]) + b2f((u16)ct[e]);
      s1 += f; s2 += f * f;
    }
  }
  s1 += __shfl_xor(s1, 1); s2 += __shfl_xor(s2, 1);
  s1 += __shfl_xor(s1, 2); s2 += __shfl_xor(s2, 2);
  float mean = s1 * (1.f / 512.f);
  float inv = rsqrtf(fmaxf(s2 * (1.f / 512.f) - mean * mean, 0.f) + 1e-5f);

  float a0 = wp[0], a1 = wp[1], a2 = wp[2], a3 = wp[3];
  float mxw = fmaxf(fmaxf(a0, a1), fmaxf(a2, a3));
  float e0 = expf(a0 - mxw), e1 = expf(a1 - mxw), e2 = expf(a2 - mxw), e3 = expf(a3 - mxw);
  float invs = 1.f / (e0 + e1 + e2 + e3);
  float w0 = e0 * invs, w1 = e1 * invs, w2 = e2 * invs, w3 = e3 * invs;

  #pragma unroll
  for (int k = 0; k < 16; ++k) {
    int c8 = part + k * 4;
    short8 t8  = *(const short8*)(rowp + c8 * 8);
    short8 ct  = *(const short8*)(ctab_bf + lrow + c8 * 8);
    short8 c8v = *(const short8*)(ce + mrow + c8 * 8);
    short8 pf  = *(const short8*)(pf_tab + lrow + c8 * 8);
    short8 pl  = *(const short8*)(pl_tab + lrow + c8 * 8);
    float o[8];
    #pragma unroll
    for (int e = 0; e < 8; ++e) {
      int d = c8 * 8 + e;
      float f = b2f((u16)t8[e]) + b2f((u16)ct[e]);
      float pt = sG[d] * ((f - mean) * inv) + sB[d];
      o[e] = w0 * b2f((u16)c8v[e]) + w1 * b2f((u16)pf[e]) + w2 * b2f((u16)pl[e]) + w3 * pt;
    }
    float4* op = (float4*)(out + mrow + c8 * 8);
    op[0] = make_float4(o[0], o[1], o[2], o[3]);
    op[1] = make_float4(o[4], o[5], o[6], o[7]);
  }
}

// ---------------------------------------------------------------------------
extern "C" void kernel_launch(void* const* d_in, const int* in_sizes, int n_in,
                              void* d_out, int out_size, void* d_ws, size_t ws_size,
                              hipStream_t stream) {
  const float* x          = (const float*)d_in[0];
  const float* conv_w     = (const float*)d_in[1];
  const float* conv_b     = (const float*)d_in[2];
  const float* learned_pe = (const float*)d_in[3];
  const float* tape_pos   = (const float*)d_in[4];
  const float* tproj_w    = (const float*)d_in[5];
  const float* tproj_b    = (const float*)d_in[6];
  const float* mixer_w    = (const float*)d_in[7];
  const float* mixer_b    = (const float*)d_in[8];
  const float* g_c        = (const float*)d_in[9];
  const float* b_c        = (const float*)d_in[10];
  const float* g_f        = (const float*)d_in[11];
  const float* b_f        = (const float*)d_in[12];
  const float* g_l        = (const float*)d_in[13];
  const float* b_l        = (const float*)d_in[14];
  const float* g_t        = (const float*)d_in[15];
  const float* b_t        = (const float*)d_in[16];
  const float* wp         = (const float*)d_in[17];

  char* ws = (char*)d_ws;
  u16*  comb    = (u16*)(ws + 0);             // 32 MiB
  u16*  ce      = (u16*)(ws + 33554432);      // 64 MiB
  char* S       = ws + 100663296;
  u16*  W1      = (u16*)(S + 0);              // 768 KiB
  u16*  A_m1    = (u16*)(S + 786432);         // 512 KiB
  u16*  M2t     = (u16*)(S + 1310720);        // 512 KiB
  u16*  tprojT  = (u16*)(S + 1835008);        // 512 KiB
  u16*  tape_bf = (u16*)(S + 2359296);        // 4 MiB
  u16*  Wf      = (u16*)(S + 6553600);        // 512 KiB
  u16*  ctab_bf = (u16*)(S + 7077888);        // 4 MiB
  float* bias2  = (float*)(S + 11272192);     // 2 KiB
  u16*  pf_tab  = (u16*)(S + 11274240);       // 4 MiB
  u16*  pl_tab  = (u16*)(S + 15468544);       // 4 MiB

  // 1) all precompute + features in one launch
  prep_all<<<14850, 256, 0, stream>>>(x, conv_w, mixer_w, tproj_w, tape_pos,
                                      tproj_b, mixer_b, learned_pe,
                                      g_f, b_f, g_l, b_l,
                                      W1, A_m1, M2t, tprojT, tape_bf,
                                      bias2, pf_tab, pl_tab, comb);
  // 2) both small GEMMs (Wf, ctab) in one launch
  gemm_bt_both<<<144, 256, 0, stream>>>(A_m1, tprojT, Wf, tape_bf, M2t,
                                        ctab_bf, bias2);
  // 3) fused conv GEMM + LN + pre GEMM + LN + weighted sum
  gemm_conv_pre<<<1024, 256, 0, stream>>>(comb, W1, conv_b, g_c, b_c,
                                          Wf, ctab_bf, pf_tab, pl_tab,
                                          g_t, b_t, wp, ce, (float*)d_out);
}